// Round 10
// baseline (257.553 us; speedup 1.0000x reference)
//
#include <hip/hip_runtime.h>
#include <stdint.h>

#define N 2048
#define DIN 128
#define H 64
#define OUTD 7
#define RS 32    // k_reduce row-splits per product
#define S1 8     // gemm1 K-splits
#define S2 8     // gemm2 K-splits

// Z6 row layout: [zt(64) | zct(64) | zf(64) | zcf(64) | Lcf(64) | Lct(64)]
#define Z_ZT  0
#define Z_ZCT 64
#define Z_ZF  128
#define Z_ZCF 192
#define Z_LCF 256
#define Z_LCT 320

typedef short bf16x8 __attribute__((ext_vector_type(8)));
typedef float floatx4 __attribute__((ext_vector_type(4)));

__device__ __forceinline__ float leaky(float x){ return x > 0.f ? x : 0.1f*x; }

__device__ __forceinline__ unsigned short f2bf(float f){
  unsigned int u = __float_as_uint(f);
  u = u + 0x7FFFu + ((u >> 16) & 1u);   // RNE
  return (unsigned short)(u >> 16);
}

__device__ __forceinline__ float bf2f(unsigned short u){
  return __uint_as_float((unsigned int)u << 16);
}

__device__ __forceinline__ float waveRedSum(float v){
  #pragma unroll
  for (int o = 32; o > 0; o >>= 1) v += __shfl_xor(v, o, 64);
  return v;
}

__device__ __forceinline__ unsigned long long shflx64(unsigned long long v, int m){
  unsigned int lo = (unsigned int)v, hi = (unsigned int)(v >> 32);
  lo = (unsigned int)__shfl_xor((int)lo, m, 64);
  hi = (unsigned int)__shfl_xor((int)hi, m, 64);
  return ((unsigned long long)hi << 32) | lo;
}

// ---------- fused: cast A->bf16 + rowsum->dA + h + hsT + sq/hsum + split-h ----------
__global__ __launch_bounds__(256) void k_preph(const float* __restrict__ A,
                    const float* __restrict__ x,
                    const float* __restrict__ W1g, const float* __restrict__ b1,
                    float* __restrict__ dA, unsigned short* __restrict__ Abf,
                    unsigned short* __restrict__ hb_hi,
                    unsigned short* __restrict__ hb_lo,
                    unsigned short* __restrict__ hsT,
                    float* __restrict__ sq, float* __restrict__ hsum){
  __shared__ float W1t[DIN][H+1];            // W1t[c][t] = W1[t][c]
  __shared__ float xb[4][DIN];
  __shared__ __align__(16) unsigned short hTb[H][16];
  __shared__ float dAl[16];
  int tid = threadIdx.x, w = tid >> 6, lane = tid & 63;
  int i0 = blockIdx.x * 16;
  // stage W1 transposed
  for (int u = tid; u < 2048; u += 256){
    float4 g = ((const float4*)W1g)[u];
    int row = u >> 5, c0 = (u & 31) * 4;
    W1t[c0+0][row] = g.x; W1t[c0+1][row] = g.y;
    W1t[c0+2][row] = g.z; W1t[c0+3][row] = g.w;
  }
  // cast + rowsum: wave w handles rows w*4..w*4+4
  for (int rr = 0; rr < 4; rr++){
    int i = i0 + w*4 + rr;
    const float4* row = (const float4*)(A + (size_t)i * N);
    unsigned short* ob = Abf + (size_t)i * N;
    float s = 0.f;
    #pragma unroll
    for (int it = 0; it < 8; it++){
      int u = it*64 + lane;
      float4 v = row[u];
      s += v.x + v.y + v.z + v.w;
      ushort4 o;
      o.x = f2bf(v.x); o.y = f2bf(v.y); o.z = f2bf(v.z); o.w = f2bf(v.w);
      *(ushort4*)&ob[u*4] = o;
    }
    s = waveRedSum(s);
    if (lane == 0){
      float d = 1.0f / sqrtf(s + 1e-10f);
      dA[i] = d; dAl[w*4+rr] = d;
    }
  }
  __syncthreads();
  int t = lane;
  float bt = b1[t];
  for (int rr = 0; rr < 4; rr++){
    int i = i0 + w*4 + rr;
    xb[w][t]      = x[(size_t)i*DIN + t];
    xb[w][t + 64] = x[(size_t)i*DIN + t + 64];
    float acc = bt;
    #pragma unroll
    for (int c4 = 0; c4 < DIN/4; c4++){
      float xv[4]; *(float4*)xv = *(const float4*)&xb[w][c4*4];
      acc += xv[0]*W1t[c4*4+0][t] + xv[1]*W1t[c4*4+1][t]
           + xv[2]*W1t[c4*4+2][t] + xv[3]*W1t[c4*4+3][t];
    }
    float hv = leaky(acc);
    unsigned short hi = f2bf(hv);
    hb_hi[(size_t)i*H + t] = hi;
    hb_lo[(size_t)i*H + t] = f2bf(hv - bf2f(hi));
    hTb[t][w*4+rr] = f2bf(dAl[w*4+rr]*hv);
    float s2 = waveRedSum(hv*hv);
    float s1 = waveRedSum(hv);
    if (t == 0){ sq[i] = s2; hsum[i] = s1; }
  }
  __syncthreads();
  { int c = tid >> 2, qq = tid & 3;
    ushort4 v = *(ushort4*)&hTb[c][qq*4];
    *(ushort4*)&hsT[(size_t)c*N + i0 + qq*4] = v; }
}

// ---------- fused gram (split-bf16 MFMA) + top-4 + cos + df, NO DOT buffer ----------
// 32 blocks x 64-row strips; wave w owns rows i0+w*16..+16; lanes own cols = ml mod 16
__global__ __launch_bounds__(256) void k_gramtop(
    const unsigned short* __restrict__ Hhi, const unsigned short* __restrict__ Hlo,
    const float* __restrict__ sq, const float* __restrict__ hsum,
    int* __restrict__ nidx, float* __restrict__ ncos, float* __restrict__ df){
  __shared__ __align__(16) unsigned short Bh[128][72];
  __shared__ __align__(16) unsigned short Bl[128][72];
  __shared__ float sqs[2048];
  int tid = threadIdx.x, w = tid >> 6, lane = tid & 63;
  int quad = lane >> 4, ml = lane & 15;
  int i0 = blockIdx.x * 64;
  for (int u = tid; u < 512; u += 256)
    ((float4*)sqs)[u] = ((const float4*)sq)[u];
  int arow = i0 + w*16 + ml;
  bf16x8 ah0 = *(const bf16x8*)(Hhi + (size_t)arow*H + quad*8);
  bf16x8 ah1 = *(const bf16x8*)(Hhi + (size_t)arow*H + 32 + quad*8);
  bf16x8 al0 = *(const bf16x8*)(Hlo + (size_t)arow*H + quad*8);
  bf16x8 al1 = *(const bf16x8*)(Hlo + (size_t)arow*H + 32 + quad*8);
  unsigned long long best[4][4];
  #pragma unroll
  for (int r = 0; r < 4; r++)
    #pragma unroll
    for (int e = 0; e < 4; e++) best[r][e] = ~0ULL;

  for (int cb = 0; cb < 16; cb++){
    int c0 = cb * 128;
    __syncthreads();
    for (int u = tid; u < 1024; u += 256){
      int r = u >> 3, s = u & 7;
      *(uint4*)&Bh[r][s*8] = *(const uint4*)(Hhi + (size_t)(c0+r)*H + s*8);
      *(uint4*)&Bl[r][s*8] = *(const uint4*)(Hlo + (size_t)(c0+r)*H + s*8);
    }
    __syncthreads();
    #pragma unroll
    for (int ct = 0; ct < 8; ct++){
      floatx4 acc = (floatx4){0.f,0.f,0.f,0.f};
      bf16x8 bh0 = *(const bf16x8*)&Bh[ct*16+ml][quad*8];
      bf16x8 bh1 = *(const bf16x8*)&Bh[ct*16+ml][32+quad*8];
      bf16x8 bl0 = *(const bf16x8*)&Bl[ct*16+ml][quad*8];
      bf16x8 bl1 = *(const bf16x8*)&Bl[ct*16+ml][32+quad*8];
      acc = __builtin_amdgcn_mfma_f32_16x16x32_bf16(ah0, bh0, acc, 0,0,0);
      acc = __builtin_amdgcn_mfma_f32_16x16x32_bf16(ah1, bh1, acc, 0,0,0);
      acc = __builtin_amdgcn_mfma_f32_16x16x32_bf16(ah0, bl0, acc, 0,0,0);
      acc = __builtin_amdgcn_mfma_f32_16x16x32_bf16(ah1, bl1, acc, 0,0,0);
      acc = __builtin_amdgcn_mfma_f32_16x16x32_bf16(al0, bh0, acc, 0,0,0);
      acc = __builtin_amdgcn_mfma_f32_16x16x32_bf16(al1, bh1, acc, 0,0,0);
      unsigned int col = (unsigned int)(c0 + ct*16 + ml);
      float sqc = sqs[col];
      #pragma unroll
      for (int r = 0; r < 4; r++){
        float kv = sqc - 2.f*acc[r];
        unsigned int uk = __float_as_uint(kv);
        uk = (uk & 0x80000000u) ? ~uk : (uk | 0x80000000u);
        unsigned long long cc = ((unsigned long long)uk << 32) | col;
        if (cc < best[r][3]){
          best[r][3] = cc;
          unsigned long long t0;
          if (best[r][3] < best[r][2]){ t0=best[r][2]; best[r][2]=best[r][3]; best[r][3]=t0; }
          if (best[r][2] < best[r][1]){ t0=best[r][1]; best[r][1]=best[r][2]; best[r][2]=t0; }
          if (best[r][1] < best[r][0]){ t0=best[r][0]; best[r][0]=best[r][1]; best[r][1]=t0; }
        }
      }
    }
  }
  // merge across the 16 lanes of each quad (disjoint column sets, same rows)
  #pragma unroll
  for (int r = 0; r < 4; r++){
    unsigned long long w0=~0ULL, w1=~0ULL, w2=~0ULL, w3=~0ULL;
    #pragma unroll
    for (int e = 0; e < 4; e++){
      unsigned long long m = best[r][0];
      unsigned long long o1 = shflx64(m, 1); if (o1 < m) m = o1;
      unsigned long long o2 = shflx64(m, 2); if (o2 < m) m = o2;
      unsigned long long o4 = shflx64(m, 4); if (o4 < m) m = o4;
      unsigned long long o8 = shflx64(m, 8); if (o8 < m) m = o8;
      if (e == 0) w0 = m; else if (e == 1) w1 = m; else if (e == 2) w2 = m; else w3 = m;
      if      (best[r][0]==m){best[r][0]=best[r][1];best[r][1]=best[r][2];best[r][2]=best[r][3];best[r][3]=~0ULL;}
      else if (best[r][1]==m){best[r][1]=best[r][2];best[r][2]=best[r][3];best[r][3]=~0ULL;}
      else if (best[r][2]==m){best[r][2]=best[r][3];best[r][3]=~0ULL;}
      else if (best[r][3]==m){best[r][3]=~0ULL;}
    }
    int rowi = i0 + w*16 + quad*4 + r;
    float myc = 0.f;
    if (ml < 4){
      unsigned long long wv = (ml==0)?w0:(ml==1)?w1:(ml==2)?w2:w3;
      unsigned int j = (unsigned int)wv;
      unsigned int uk = (unsigned int)(wv >> 32);
      float key = (uk & 0x80000000u) ? __uint_as_float(uk ^ 0x80000000u)
                                     : __uint_as_float(~uk);
      float sqj = sqs[j];
      float dot = (sqj - key) * 0.5f;
      float hni = sqrtf(sqs[rowi]), hnj = sqrtf(sqj);
      float cosv = dot/(hni*hnj)
                 + 1e-10f*(hsum[rowi]/hni + hsum[j]/hnj)
                 + 64.0f*1e-20f;
      nidx[rowi*4 + ml] = (int)j;
      ncos[rowi*4 + ml] = cosv;
      myc = cosv;
    }
    myc += __shfl_xor(myc, 1, 64);
    myc += __shfl_xor(myc, 2, 64);
    if (ml == 0) df[rowi] = 1.f / sqrtf(myc + 1e-10f);
  }
}

// ---------- MFMA bf16 GEMM: Cp[ks] = Abf[:, ksl] @ BtG^T[ksl, :] ----------
template<int BN>
__global__ __launch_bounds__(256) void k_mgemm(
    const unsigned short* __restrict__ Abf, const unsigned short* __restrict__ BtG,
    float* __restrict__ Cp, int KC){
  __shared__ __align__(16) unsigned short Asl[64][72];
  __shared__ __align__(16) unsigned short Bsl[BN][72];
  int m0 = blockIdx.x * 64, kbase = blockIdx.y * KC;
  int tid = threadIdx.x;
  int w = tid >> 6, lane = tid & 63;
  int quad = lane >> 4, ml = lane & 15;
  floatx4 acc[BN/16];
  #pragma unroll
  for (int ct = 0; ct < BN/16; ct++) acc[ct] = (floatx4){0.f,0.f,0.f,0.f};

  for (int kc = 0; kc < KC; kc += 64){
    int kb = kbase + kc;
    #pragma unroll
    for (int u = tid; u < 512; u += 256){
      int r = u >> 3, s = u & 7;
      *(uint4*)&Asl[r][s*8] = *(const uint4*)(Abf + ((size_t)(m0+r) << 11) + kb + s*8);
    }
    #pragma unroll
    for (int u = tid; u < BN*8; u += 256){
      int n = u >> 3, s = u & 7;
      *(uint4*)&Bsl[n][s*8] = *(const uint4*)(BtG + ((size_t)n << 11) + kb + s*8);
    }
    __syncthreads();
    #pragma unroll
    for (int k0 = 0; k0 < 64; k0 += 32){
      bf16x8 af = *(const bf16x8*)&Asl[16*w + ml][k0 + quad*8];
      #pragma unroll
      for (int ct = 0; ct < BN/16; ct++){
        bf16x8 bfr = *(const bf16x8*)&Bsl[16*ct + ml][k0 + quad*8];
        acc[ct] = __builtin_amdgcn_mfma_f32_16x16x32_bf16(af, bfr, acc[ct], 0, 0, 0);
      }
    }
    __syncthreads();
  }
  float* C = Cp + (size_t)blockIdx.y * (N * BN);
  #pragma unroll
  for (int ct = 0; ct < BN/16; ct++)
    #pragma unroll
    for (int r = 0; r < 4; r++){
      int row = m0 + 16*w + quad*4 + r;
      C[(size_t)row*BN + 16*ct + ml] = acc[ct][r];
    }
}

// ---------- z1 layers via MFMA, fused gather (p0/p1) + partial-sum (p2/p3) ----------
__global__ __launch_bounds__(256) void k_z1m(
    const unsigned short* __restrict__ hb,
    const int* __restrict__ nidx, const float* __restrict__ ncos,
    const float* __restrict__ df,
    const float* __restrict__ Y1p, const float* __restrict__ dA,
    const float* __restrict__ WF1, const float* __restrict__ WC1,
    const float* __restrict__ WT1, const float* __restrict__ bF1,
    const float* __restrict__ bC1, const float* __restrict__ bT1,
    float* __restrict__ z1f, float* __restrict__ z1cf,
    unsigned short* __restrict__ ZsT){
  __shared__ __align__(16) unsigned short Vs[64][72];
  __shared__ __align__(16) unsigned short Ws[64][72];
  __shared__ __align__(16) unsigned short Tb[64][72];
  __shared__ float bias[64], dAl[64];
  int p = blockIdx.y, i0 = blockIdx.x * 64, tid = threadIdx.x;
  int w = tid >> 6, lane = tid & 63;
  const float* Wsrc = (p == 0) ? WF1 : (p == 2) ? WT1 : WC1;
  const float* bsrc = (p == 0) ? bF1 : (p == 2) ? bT1 : bC1;
  for (int u = tid; u < 1024; u += 256){
    int r = u >> 4, c4 = (u & 15)*4;
    float4 f = *(const float4*)(Wsrc + (size_t)r*H + c4);
    Ws[r][c4+0] = f2bf(f.x); Ws[r][c4+1] = f2bf(f.y);
    Ws[r][c4+2] = f2bf(f.z); Ws[r][c4+3] = f2bf(f.w);
  }
  if (tid < 64){ bias[tid] = bsrc[tid]; dAl[tid] = dA[i0 + tid]; }
  if (p < 2){
    for (int rr = 0; rr < 16; rr++){
      int r = w*16 + rr, i = i0 + r;
      int j0 = nidx[i*4], j1 = nidx[i*4+1], j2 = nidx[i*4+2], j3 = nidx[i*4+3];
      float di = df[i];
      float w0 = ncos[i*4]  *di*df[j0];
      float w1 = ncos[i*4+1]*di*df[j1];
      float w2 = ncos[i*4+2]*di*df[j2];
      float w3 = ncos[i*4+3]*di*df[j3];
      float v = w0*bf2f(hb[(size_t)j0*H+lane]) + w1*bf2f(hb[(size_t)j1*H+lane])
              + w2*bf2f(hb[(size_t)j2*H+lane]) + w3*bf2f(hb[(size_t)j3*H+lane]);
      Vs[r][lane] = f2bf(v);
    }
  } else {
    for (int u = tid; u < 1024; u += 256){
      int r = u >> 4, k4 = u & 15;
      const float* base = Y1p + (size_t)(i0 + r)*H + k4*4;
      float4 s = *(const float4*)base;
      #pragma unroll
      for (int pp = 1; pp < S1; pp++){
        float4 v2 = *(const float4*)(base + (size_t)pp*N*H);
        s.x += v2.x; s.y += v2.y; s.z += v2.z; s.w += v2.w;
      }
      float d = dA[i0 + r];
      Vs[r][k4*4+0] = f2bf(s.x*d); Vs[r][k4*4+1] = f2bf(s.y*d);
      Vs[r][k4*4+2] = f2bf(s.z*d); Vs[r][k4*4+3] = f2bf(s.w*d);
    }
  }
  __syncthreads();
  int quad = lane >> 4, ml = lane & 15;
  floatx4 acc[4];
  #pragma unroll
  for (int ct = 0; ct < 4; ct++) acc[ct] = (floatx4){0.f,0.f,0.f,0.f};
  #pragma unroll
  for (int k0 = 0; k0 < 64; k0 += 32){
    bf16x8 af = *(const bf16x8*)&Vs[16*w + ml][k0 + quad*8];
    #pragma unroll
    for (int ct = 0; ct < 4; ct++){
      bf16x8 bfr = *(const bf16x8*)&Ws[16*ct + ml][k0 + quad*8];
      acc[ct] = __builtin_amdgcn_mfma_f32_16x16x32_bf16(af, bfr, acc[ct], 0, 0, 0);
    }
  }
  if (p < 2){
    float* dst = (p == 0) ? z1f : z1cf;
    #pragma unroll
    for (int ct = 0; ct < 4; ct++){
      int col = 16*ct + ml;
      #pragma unroll
      for (int r = 0; r < 4; r++){
        int row = 16*w + quad*4 + r;
        dst[(size_t)(i0+row)*H + col] = leaky(acc[ct][r] + bias[col]);
      }
    }
  } else {
    #pragma unroll
    for (int ct = 0; ct < 4; ct++){
      int col = 16*ct + ml;
      #pragma unroll
      for (int r = 0; r < 4; r++){
        int row = 16*w + quad*4 + r;
        Tb[col][row] = f2bf(dAl[row] * leaky(acc[ct][r] + bias[col]));
      }
    }
    __syncthreads();
    int zb = (p == 2) ? 0 : 64;
    #pragma unroll
    for (int u = tid; u < 512; u += 256){
      int c = u >> 3, s = u & 7;
      *(uint4*)&ZsT[(size_t)(zb + c)*N + i0 + s*8] = *(uint4*)&Tb[c][s*8];
    }
  }
}

// ---------- z2 layers via MFMA, fused gather (p0/p1) + partial-sum (p2/p3) ----------
__global__ __launch_bounds__(256) void k_z2m(
    const float* __restrict__ z1f, const float* __restrict__ z1cf,
    const int* __restrict__ nidx, const float* __restrict__ ncos,
    const float* __restrict__ df,
    const float* __restrict__ Y2p, const float* __restrict__ dA,
    const float* __restrict__ WF2, const float* __restrict__ WC2,
    const float* __restrict__ WT2, const float* __restrict__ bF2,
    const float* __restrict__ bC2, const float* __restrict__ bT2,
    float* __restrict__ Z6){
  __shared__ __align__(16) unsigned short Vs[64][72];
  __shared__ __align__(16) unsigned short Ws[64][72];
  __shared__ float bias[64];
  int p = blockIdx.y, i0 = blockIdx.x * 64, tid = threadIdx.x;
  int w = tid >> 6, lane = tid & 63;
  const float* Wsrc = (p == 0) ? WF2 : (p == 2) ? WT2 : WC2;
  const float* bsrc = (p == 0) ? bF2 : (p == 2) ? bT2 : bC2;
  for (int u = tid; u < 1024; u += 256){
    int r = u >> 4, c4 = (u & 15)*4;
    float4 f = *(const float4*)(Wsrc + (size_t)r*H + c4);
    Ws[r][c4+0] = f2bf(f.x); Ws[r][c4+1] = f2bf(f.y);
    Ws[r][c4+2] = f2bf(f.z); Ws[r][c4+3] = f2bf(f.w);
  }
  if (tid < 64) bias[tid] = bsrc[tid];
  if (p < 2){
    const float* src = (p == 0) ? z1f : z1cf;
    for (int rr = 0; rr < 16; rr++){
      int r = w*16 + rr, i = i0 + r;
      int j0 = nidx[i*4], j1 = nidx[i*4+1], j2 = nidx[i*4+2], j3 = nidx[i*4+3];
      float di = df[i];
      float w0 = ncos[i*4]  *di*df[j0];
      float w1 = ncos[i*4+1]*di*df[j1];
      float w2 = ncos[i*4+2]*di*df[j2];
      float w3 = ncos[i*4+3]*di*df[j3];
      float v = w0*src[(size_t)j0*H+lane] + w1*src[(size_t)j1*H+lane]
              + w2*src[(size_t)j2*H+lane] + w3*src[(size_t)j3*H+lane];
      Vs[r][lane] = f2bf(v);
    }
  } else {
    int off = (p == 2) ? 0 : 64;
    for (int u = tid; u < 1024; u += 256){
      int r = u >> 4, k4 = u & 15;
      const float* base = Y2p + (size_t)(i0 + r)*128 + off + k4*4;
      float4 s = *(const float4*)base;
      #pragma unroll
      for (int pp = 1; pp < S2; pp++){
        float4 v2 = *(const float4*)(base + (size_t)pp*N*128);
        s.x += v2.x; s.y += v2.y; s.z += v2.z; s.w += v2.w;
      }
      float d = dA[i0 + r];
      Vs[r][k4*4+0] = f2bf(s.x*d); Vs[r][k4*4+1] = f2bf(s.y*d);
      Vs[r][k4*4+2] = f2bf(s.z*d); Vs[r][k4*4+3] = f2bf(s.w*d);
    }
  }
  __syncthreads();
  int quad = lane >> 4, ml = lane & 15;
  floatx4 acc[4];
  #pragma unroll
  for (int ct = 0; ct < 4; ct++) acc[ct] = (floatx4){0.f,0.f,0.f,0.f};
  #pragma unroll
  for (int k0 = 0; k0 < 64; k0 += 32){
    bf16x8 af = *(const bf16x8*)&Vs[16*w + ml][k0 + quad*8];
    #pragma unroll
    for (int ct = 0; ct < 4; ct++){
      bf16x8 bfr = *(const bf16x8*)&Ws[16*ct + ml][k0 + quad*8];
      acc[ct] = __builtin_amdgcn_mfma_f32_16x16x32_bf16(af, bfr, acc[ct], 0, 0, 0);
    }
  }
  int zoff = (p == 0) ? Z_ZF : (p == 1) ? Z_ZCF : (p == 2) ? Z_ZT : Z_ZCT;
  float val[4][4];
  #pragma unroll
  for (int ct = 0; ct < 4; ct++){
    int col = 16*ct + ml;
    #pragma unroll
    for (int r = 0; r < 4; r++){
      val[ct][r] = leaky(acc[ct][r] + bias[col]);
      int row = 16*w + quad*4 + r;
      Z6[(size_t)(i0+row)*384 + zoff + col] = val[ct][r];
    }
  }
  if (p == 1 || p == 3){
    int loff = (p == 1) ? Z_LCF : Z_LCT;
    #pragma unroll
    for (int r = 0; r < 4; r++){
      float s = val[0][r]*val[0][r] + val[1][r]*val[1][r]
              + val[2][r]*val[2][r] + val[3][r]*val[3][r];
      s += __shfl_xor(s, 1, 64); s += __shfl_xor(s, 2, 64);
      s += __shfl_xor(s, 4, 64); s += __shfl_xor(s, 8, 64);
      float m = sqrtf(s*(1.f/64.f)) + 1e-10f;
      int row = 16*w + quad*4 + r;
      #pragma unroll
      for (int ct = 0; ct < 4; ct++)
        Z6[(size_t)(i0+row)*384 + loff + 16*ct + ml] = val[ct][r]/m;
    }
  }
}

// ---------- fused attention+out (blocks 0..511) and reduce (blocks 512..671) ----------
__global__ __launch_bounds__(256) void k_attred(const float* __restrict__ Z6,
    const float* __restrict__ Wag, const float* __restrict__ ba,
    const float* __restrict__ q, const float* __restrict__ W2g,
    const float* __restrict__ b2, float* __restrict__ out,
    float* __restrict__ redP, float* __restrict__ colP){
  __shared__ float Wal[64][65];
  __shared__ float W2l[448];
  __shared__ float zbuf[4][3][66];
  __shared__ float zagg[4][66];
  __shared__ float sa[64][68];
  __shared__ float sb[64][68];
  int tid = threadIdx.x, w = tid >> 6, t = tid & 63;
  if (blockIdx.x < 512){
    for (int u = tid; u < 1024; u += 256){
      int r = u >> 4, c4 = (u & 15)*4;
      float4 f = ((const float4*)Wag)[u];
      Wal[r][c4+0]=f.x; Wal[r][c4+1]=f.y; Wal[r][c4+2]=f.z; Wal[r][c4+3]=f.w;
    }
    if (tid < 112) *(float4*)&W2l[tid*4] = ((const float4*)W2g)[tid];
    __syncthreads();
    int i = blockIdx.x*4 + w;
    const float* zr = Z6 + (size_t)i*384;
    float zf = zr[Z_ZF + t], zt = zr[Z_ZT + t];
    float zc = 0.5f*(zr[Z_ZCF + t] + zr[Z_ZCT + t]);
    zbuf[w][0][t] = zf; zbuf[w][1][t] = zt; zbuf[w][2][t] = zc;
    __syncthreads();
    float bav = ba[t], qv = q[t];
    float e[3];
    #pragma unroll
    for (int k = 0; k < 3; k++){
      float S = bav;
      #pragma unroll 8
      for (int c = 0; c < 64; c++) S += zbuf[w][k][c] * Wal[t][c];
      e[k] = waveRedSum(tanhf(S)*qv);
    }
    float mx = fmaxf(e[0], fmaxf(e[1], e[2]));
    float x0 = expf(e[0]-mx), x1 = expf(e[1]-mx), x2 = expf(e[2]-mx);
    float inv = 1.f/(x0+x1+x2);
    zagg[w][t] = x0*inv*zf + x1*inv*zt + x2*inv*zc;
    __syncthreads();
    if (t < OUTD){
      float acc = b2[t];
      #pragma unroll 8
      for (int c = 0; c < 64; c++) acc += zagg[w][c]*W2l[t*64 + c];
      out[(size_t)i*OUTD + t] = acc;
    }
  } else {
    int bb = blockIdx.x - 512;
    int p = bb >> 5, s = bb & 31;
    const int aoffT[5] = {Z_ZT,  Z_ZF,  Z_LCF, Z_LCF, Z_LCT};
    const int boffT[5] = {Z_ZCT, Z_ZCF, Z_LCF, Z_LCT, Z_LCT};
    int aoff = aoffT[p], boff = boffT[p];
    int r0 = s * 64;
    {
      int row = tid >> 4, c4 = (tid & 15) * 4;
      #pragma unroll
      for (int rr = 0; rr < 64; rr += 16){
        const float* zr = Z6 + (size_t)(r0 + row + rr) * 384;
        *(float4*)&sa[row + rr][c4] = *(const float4*)&zr[aoff + c4];
        *(float4*)&sb[row + rr][c4] = *(const float4*)&zr[boff + c4];
      }
    }
    __syncthreads();
    int rg = tid >> 4, cg = tid & 15;
    float acc[4][4] = {};
    #pragma unroll 8
    for (int k = 0; k < 64; k++){
      float a[4], b[4];
      *(float4*)a = *(const float4*)&sa[k][rg*4];
      *(float4*)b = *(const float4*)&sb[k][cg*4];
      #pragma unroll
      for (int ii = 0; ii < 4; ii++)
        #pragma unroll
        for (int jj = 0; jj < 4; jj++)
          acc[ii][jj] += a[ii]*b[jj];
    }
    float* rp = redP + (size_t)bb * 4096;
    #pragma unroll
    for (int ii = 0; ii < 4; ii++)
      *(float4*)&rp[(rg*4+ii)*64 + cg*4] =
        make_float4(acc[ii][0], acc[ii][1], acc[ii][2], acc[ii][3]);
    if (p < 2 && tid < 128){
      int tt = tid & 63;
      float csum = 0.f;
      if (tid < 64){
        #pragma unroll 16
        for (int r = 0; r < 64; r++) csum += sa[r][tt];
      } else {
        #pragma unroll 16
        for (int r = 0; r < 64; r++) csum += sb[r][tt];
      }
      colP[((size_t)p*RS + s)*128 + tid] = csum;
    }
  }
}

// ---------- sum partial slabs into red ----------
__global__ void k_combine(const float* __restrict__ redP,
                          const float* __restrict__ colP,
                          float* __restrict__ red){
  int idx = blockIdx.x*256 + threadIdx.x;
  if (idx < 20480){
    int p = idx >> 12, i = idx & 4095;
    float sum = 0.f;
    #pragma unroll 8
    for (int s = 0; s < RS; s++) sum += redP[((size_t)p*RS + s)*4096 + i];
    red[idx] = sum;
  } else if (idx < 20736){
    int j = idx - 20480;
    int p = j >> 7, rem = j & 127;
    float sum = 0.f;
    #pragma unroll 8
    for (int s = 0; s < RS; s++) sum += colP[((size_t)p*RS + s)*128 + rem];
    red[idx] = sum;
  }
}

// ---------- final scalars Lc, Ld ----------
__global__ void k_final(const float* __restrict__ red, float* __restrict__ out2){
  int tid = threadIdx.x;
  const float* Stc = red;
  const float* Sfc = red + 4096;
  const float* Cff = red + 8192;
  const float* Cft = red + 12288;
  const float* Ctt = red + 16384;
  const float* cst = red + 20480;
  const float* csct= red + 20544;
  const float* csf = red + 20608;
  const float* cscf= red + 20672;
  float sCff=0, sCft=0, sCtt=0, sM1=0, sM2=0;
  for (int u = tid*16; u < tid*16+16; u++){
    int d = u >> 6, e = u & 63;
    float m1 = Stc[u] - cst[d]*csct[e]*(1.f/2048.f);
    float m2 = Sfc[u] - csf[d]*cscf[e]*(1.f/2048.f);
    sM1 += m1*m1; sM2 += m2*m2;
    float cf = Cff[u], cx = Cft[u], ct = Ctt[u];
    sCff += cf*cf; sCft += cx*cx; sCtt += ct*ct;
  }
  __shared__ float rd[5][4];
  sCff = waveRedSum(sCff); sCft = waveRedSum(sCft); sCtt = waveRedSum(sCtt);
  sM1 = waveRedSum(sM1);   sM2 = waveRedSum(sM2);
  int w = tid >> 6, lane = tid & 63;
  if (lane == 0){ rd[0][w]=sCff; rd[1][w]=sCft; rd[2][w]=sCtt; rd[3][w]=sM1; rd[4][w]=sM2; }
  __syncthreads();
  if (tid == 0){
    float A0 = rd[0][0]+rd[0][1]+rd[0][2]+rd[0][3];
    float A1 = rd[1][0]+rd[1][1]+rd[1][2]+rd[1][3];
    float A2 = rd[2][0]+rd[2][1]+rd[2][2]+rd[2][3];
    float M1 = rd[3][0]+rd[3][1]+rd[3][2]+rd[3][3];
    float M2 = rd[4][0]+rd[4][1]+rd[4][2]+rd[4][3];
    out2[0] = (A0 - 2.f*A1 + A2) * (1.f/(2048.f*2048.f));
    out2[1] = (M1 + M2) * (1.f/(2047.f*2047.f));
  }
}

extern "C" void kernel_launch(void* const* d_in, const int* in_sizes, int n_in,
                              void* d_out, int out_size, void* d_ws, size_t ws_size,
                              hipStream_t stream) {
  const float* x   = (const float*)d_in[0];
  const float* A   = (const float*)d_in[1];
  const float* W1  = (const float*)d_in[3];
  const float* b1  = (const float*)d_in[4];
  const float* WF1 = (const float*)d_in[5];
  const float* bF1 = (const float*)d_in[6];
  const float* WF2 = (const float*)d_in[7];
  const float* bF2 = (const float*)d_in[8];
  const float* WT1 = (const float*)d_in[9];
  const float* bT1 = (const float*)d_in[10];
  const float* WT2 = (const float*)d_in[11];
  const float* bT2 = (const float*)d_in[12];
  const float* WC1 = (const float*)d_in[13];
  const float* bC1 = (const float*)d_in[14];
  const float* WC2 = (const float*)d_in[15];
  const float* bC2 = (const float*)d_in[16];
  const float* Wa  = (const float*)d_in[17];
  const float* ba  = (const float*)d_in[18];
  const float* q   = (const float*)d_in[19];
  const float* W2  = (const float*)d_in[20];
  const float* b2  = (const float*)d_in[21];
  float* out = (float*)d_out;

  float* W = (float*)d_ws;
  float* dA   = W;                      // N
  float* sq   = dA  + N;                // N
  float* hsum = sq  + N;                // N
  float* df   = hsum+ N;                // N
  int*   nidx = (int*)(df + N);         // N*4
  float* ncos = (float*)(nidx + N*4);   // N*4
  float* red  = ncos + N*4;             // 20736
  float* Z6   = red + 20736;            // N*384
  float* Y1p  = Z6  + (size_t)N*384;    // S1*N*H
  float* Y2p  = Y1p + (size_t)S1*N*H;   // S2*N*128
  float* z1f  = Y2p + (size_t)S2*N*128; // N*H
  float* z1cf = z1f + N*H;              // N*H
  float* redP = z1cf+ N*H;              // 5*RS*4096 = 655360
  float* colP = redP+ 655360;           // 2*RS*128 = 8192
  unsigned short* Abf  = (unsigned short*)(colP + 8192);  // N*N bf16
  unsigned short* hsT  = Abf + (size_t)N*N;               // 64*N
  unsigned short* ZsT  = hsT + (size_t)H*N;               // 128*N
  unsigned short* hbHi = ZsT + (size_t)128*N;             // N*64
  unsigned short* hbLo = hbHi + (size_t)N*H;              // N*64

  k_preph<<<128, 256, 0, stream>>>(A, x, W1, b1, dA, Abf, hbHi, hbLo, hsT, sq, hsum);
  k_gramtop<<<32, 256, 0, stream>>>(hbHi, hbLo, sq, hsum, nidx, ncos, df);
  k_mgemm<64><<<dim3(32,S1), 256, 0, stream>>>(Abf, hsT, Y1p, N/S1);
  k_z1m<<<dim3(32,4), 256, 0, stream>>>(hbHi, nidx, ncos, df, Y1p, dA,
                                        WF1, WC1, WT1, bF1, bC1, bT1,
                                        z1f, z1cf, ZsT);
  k_mgemm<128><<<dim3(32,S2), 256, 0, stream>>>(Abf, ZsT, Y2p, N/S2);
  k_z2m<<<dim3(32,4), 256, 0, stream>>>(z1f, z1cf, nidx, ncos, df, Y2p, dA,
                                        WF2, WC2, WT2, bF2, bC2, bT2, Z6);
  k_attred<<<672, 256, 0, stream>>>(Z6, Wa, ba, q, W2, b2, out, redP, colP);
  k_combine<<<81, 256, 0, stream>>>(redP, colP, red);
  k_final<<<1, 256, 0, stream>>>(red, out + (size_t)N*OUTD);
}

// Round 11
// 199.282 us; speedup vs baseline: 1.2924x; 1.2924x over previous
//
#include <hip/hip_runtime.h>
#include <stdint.h>

#define N 2048
#define DIN 128
#define H 64
#define OUTD 7
#define RS 32    // k_reduce row-splits per product
#define S1 8     // gemm1 K-splits
#define S2 8     // gemm2 K-splits

// Z6 row layout: [zt(64) | zct(64) | zf(64) | zcf(64) | Lcf(64) | Lct(64)]
#define Z_ZT  0
#define Z_ZCT 64
#define Z_ZF  128
#define Z_ZCF 192
#define Z_LCF 256
#define Z_LCT 320

typedef short bf16x8 __attribute__((ext_vector_type(8)));
typedef float floatx4 __attribute__((ext_vector_type(4)));

__device__ __forceinline__ float leaky(float x){ return x > 0.f ? x : 0.1f*x; }

__device__ __forceinline__ unsigned short f2bf(float f){
  unsigned int u = __float_as_uint(f);
  u = u + 0x7FFFu + ((u >> 16) & 1u);   // RNE
  return (unsigned short)(u >> 16);
}

__device__ __forceinline__ float bf2f(unsigned short u){
  return __uint_as_float((unsigned int)u << 16);
}

__device__ __forceinline__ float waveRedSum(float v){
  #pragma unroll
  for (int o = 32; o > 0; o >>= 1) v += __shfl_xor(v, o, 64);
  return v;
}

__device__ __forceinline__ unsigned long long shflx64(unsigned long long v, int m){
  unsigned int lo = (unsigned int)v, hi = (unsigned int)(v >> 32);
  lo = (unsigned int)__shfl_xor((int)lo, m, 64);
  hi = (unsigned int)__shfl_xor((int)hi, m, 64);
  return ((unsigned long long)hi << 32) | lo;
}

// ---------- fused: cast A->bf16 + rowsum->dA + h + hsT + sq/hsum + split-h ----------
__global__ __launch_bounds__(256) void k_preph(const float* __restrict__ A,
                    const float* __restrict__ x,
                    const float* __restrict__ W1g, const float* __restrict__ b1,
                    float* __restrict__ dA, unsigned short* __restrict__ Abf,
                    unsigned short* __restrict__ hb_hi,
                    unsigned short* __restrict__ hb_lo,
                    unsigned short* __restrict__ hsT,
                    float* __restrict__ sq, float* __restrict__ hsum){
  __shared__ float W1t[DIN][H+1];            // W1t[c][t] = W1[t][c]
  __shared__ float xb[4][DIN];
  __shared__ __align__(16) unsigned short hTb[H][16];
  __shared__ float dAl[16];
  int tid = threadIdx.x, w = tid >> 6, lane = tid & 63;
  int i0 = blockIdx.x * 16;
  for (int u = tid; u < 2048; u += 256){
    float4 g = ((const float4*)W1g)[u];
    int row = u >> 5, c0 = (u & 31) * 4;
    W1t[c0+0][row] = g.x; W1t[c0+1][row] = g.y;
    W1t[c0+2][row] = g.z; W1t[c0+3][row] = g.w;
  }
  for (int rr = 0; rr < 4; rr++){
    int i = i0 + w*4 + rr;
    const float4* row = (const float4*)(A + (size_t)i * N);
    unsigned short* ob = Abf + (size_t)i * N;
    float s = 0.f;
    #pragma unroll
    for (int it = 0; it < 8; it++){
      int u = it*64 + lane;
      float4 v = row[u];
      s += v.x + v.y + v.z + v.w;
      ushort4 o;
      o.x = f2bf(v.x); o.y = f2bf(v.y); o.z = f2bf(v.z); o.w = f2bf(v.w);
      *(ushort4*)&ob[u*4] = o;
    }
    s = waveRedSum(s);
    if (lane == 0){
      float d = 1.0f / sqrtf(s + 1e-10f);
      dA[i] = d; dAl[w*4+rr] = d;
    }
  }
  __syncthreads();
  int t = lane;
  float bt = b1[t];
  for (int rr = 0; rr < 4; rr++){
    int i = i0 + w*4 + rr;
    xb[w][t]      = x[(size_t)i*DIN + t];
    xb[w][t + 64] = x[(size_t)i*DIN + t + 64];
    float acc = bt;
    #pragma unroll
    for (int c4 = 0; c4 < DIN/4; c4++){
      float xv[4]; *(float4*)xv = *(const float4*)&xb[w][c4*4];
      acc += xv[0]*W1t[c4*4+0][t] + xv[1]*W1t[c4*4+1][t]
           + xv[2]*W1t[c4*4+2][t] + xv[3]*W1t[c4*4+3][t];
    }
    float hv = leaky(acc);
    unsigned short hi = f2bf(hv);
    hb_hi[(size_t)i*H + t] = hi;
    hb_lo[(size_t)i*H + t] = f2bf(hv - bf2f(hi));
    hTb[t][w*4+rr] = f2bf(dAl[w*4+rr]*hv);
    float s2 = waveRedSum(hv*hv);
    float s1 = waveRedSum(hv);
    if (t == 0){ sq[i] = s2; hsum[i] = s1; }
  }
  __syncthreads();
  { int c = tid >> 2, qq = tid & 3;
    ushort4 v = *(ushort4*)&hTb[c][qq*4];
    *(ushort4*)&hsT[(size_t)c*N + i0 + qq*4] = v; }
}

// ---------- DOT = h @ h^T via split-bf16 MFMA (fp32-accurate) ----------
__global__ __launch_bounds__(256) void k_gram2(
    const unsigned short* __restrict__ Hhi, const unsigned short* __restrict__ Hlo,
    float* __restrict__ DOT){
  __shared__ __align__(16) unsigned short Bh[128][72];
  __shared__ __align__(16) unsigned short Bl[128][72];
  int bi = blockIdx.x, bj = blockIdx.y, tid = threadIdx.x;
  for (int u = tid; u < 1024; u += 256){
    int r = u >> 3, s = u & 7;
    *(uint4*)&Bh[r][s*8] = *(const uint4*)(Hhi + (size_t)(bj*128+r)*H + s*8);
    *(uint4*)&Bl[r][s*8] = *(const uint4*)(Hlo + (size_t)(bj*128+r)*H + s*8);
  }
  __syncthreads();
  int w = tid >> 6, lane = tid & 63, quad = lane >> 4, ml = lane & 15;
  floatx4 acc[2][8];
  #pragma unroll
  for (int rt = 0; rt < 2; rt++)
    #pragma unroll
    for (int ct = 0; ct < 8; ct++) acc[rt][ct] = (floatx4){0.f,0.f,0.f,0.f};
  #pragma unroll
  for (int rt = 0; rt < 2; rt++){
    int arow = bi*128 + (2*w + rt)*16 + ml;
    #pragma unroll
    for (int k0 = 0; k0 < 64; k0 += 32){
      bf16x8 ah = *(const bf16x8*)(Hhi + (size_t)arow*H + k0 + quad*8);
      bf16x8 al = *(const bf16x8*)(Hlo + (size_t)arow*H + k0 + quad*8);
      #pragma unroll
      for (int ct = 0; ct < 8; ct++){
        bf16x8 bh = *(const bf16x8*)&Bh[ct*16 + ml][k0 + quad*8];
        bf16x8 bl = *(const bf16x8*)&Bl[ct*16 + ml][k0 + quad*8];
        acc[rt][ct] = __builtin_amdgcn_mfma_f32_16x16x32_bf16(ah, bh, acc[rt][ct], 0,0,0);
        acc[rt][ct] = __builtin_amdgcn_mfma_f32_16x16x32_bf16(ah, bl, acc[rt][ct], 0,0,0);
        acc[rt][ct] = __builtin_amdgcn_mfma_f32_16x16x32_bf16(al, bh, acc[rt][ct], 0,0,0);
      }
    }
  }
  #pragma unroll
  for (int rt = 0; rt < 2; rt++)
    #pragma unroll
    for (int ct = 0; ct < 8; ct++)
      #pragma unroll
      for (int r = 0; r < 4; r++){
        int row = bi*128 + (2*w+rt)*16 + quad*4 + r;
        DOT[(size_t)row*N + bj*128 + ct*16 + ml] = acc[rt][ct][r];
      }
}

// ---------- per-row top-4 + cos vals + df: 4 rows/block, 1 row/wave ----------
__global__ __launch_bounds__(256) void k_topk(const float* __restrict__ DOT,
      const float* __restrict__ sq, const float* __restrict__ hsum,
      int* __restrict__ nidx, float* __restrict__ ncos, float* __restrict__ df){
  int tid = threadIdx.x, w = tid >> 6, lane = tid & 63;
  int i = blockIdx.x*4 + w;
  const float4* row = (const float4*)(DOT + (size_t)i * N);
  const float4* sq4 = (const float4*)sq;
  unsigned long long best[4] = {~0ULL, ~0ULL, ~0ULL, ~0ULL};
  #pragma unroll
  for (int it = 0; it < 8; it++){
    int u = it*64 + lane;
    float4 d = row[u];
    float4 s = sq4[u];
    float kv[4] = { s.x - 2.f*d.x, s.y - 2.f*d.y, s.z - 2.f*d.z, s.w - 2.f*d.w };
    #pragma unroll
    for (int e = 0; e < 4; e++){
      unsigned int j = (unsigned int)(u*4 + e);
      unsigned int uk = __float_as_uint(kv[e]);
      uk = (uk & 0x80000000u) ? ~uk : (uk | 0x80000000u);
      unsigned long long c = ((unsigned long long)uk << 32) | j;
      if (c < best[3]){
        best[3] = c;
        unsigned long long t0;
        if (best[3] < best[2]){ t0 = best[2]; best[2] = best[3]; best[3] = t0; }
        if (best[2] < best[1]){ t0 = best[1]; best[1] = best[2]; best[2] = t0; }
        if (best[1] < best[0]){ t0 = best[0]; best[0] = best[1]; best[1] = t0; }
      }
    }
  }
  unsigned long long win[4];
  #pragma unroll
  for (int r = 0; r < 4; r++){
    unsigned long long m = best[0];
    #pragma unroll
    for (int o = 1; o < 64; o <<= 1){
      unsigned long long other = shflx64(m, o);
      if (other < m) m = other;
    }
    win[r] = m;
    if      (best[0]==m){best[0]=best[1];best[1]=best[2];best[2]=best[3];best[3]=~0ULL;}
    else if (best[1]==m){best[1]=best[2];best[2]=best[3];best[3]=~0ULL;}
    else if (best[2]==m){best[2]=best[3];best[3]=~0ULL;}
    else if (best[3]==m){best[3]=~0ULL;}
  }
  float myc = 0.f;
  if (lane < 4){
    unsigned long long wv = win[lane];
    unsigned int j = (unsigned int)wv;
    unsigned int uk = (unsigned int)(wv >> 32);
    float key = (uk & 0x80000000u) ? __uint_as_float(uk ^ 0x80000000u)
                                   : __uint_as_float(~uk);
    float sqj = sq[j];
    float dot = (sqj - key) * 0.5f;
    float hni = sqrtf(sq[i]), hnj = sqrtf(sqj);
    float cosv = dot/(hni*hnj)
               + 1e-10f*(hsum[i]/hni + hsum[j]/hnj)
               + 64.0f*1e-20f;
    nidx[i*4 + lane] = (int)j;
    ncos[i*4 + lane] = cosv;
    myc = cosv;
  }
  myc += __shfl_xor(myc, 1, 64);
  myc += __shfl_xor(myc, 2, 64);
  if (lane == 0) df[i] = 1.f / sqrtf(myc + 1e-10f);
}

// ---------- MFMA bf16 GEMM: Cp[ks] = Abf[:, ksl] @ BtG^T[ksl, :] ----------
template<int BN>
__global__ __launch_bounds__(256) void k_mgemm(
    const unsigned short* __restrict__ Abf, const unsigned short* __restrict__ BtG,
    float* __restrict__ Cp, int KC){
  __shared__ __align__(16) unsigned short Asl[64][72];
  __shared__ __align__(16) unsigned short Bsl[BN][72];
  int m0 = blockIdx.x * 64, kbase = blockIdx.y * KC;
  int tid = threadIdx.x;
  int w = tid >> 6, lane = tid & 63;
  int quad = lane >> 4, ml = lane & 15;
  floatx4 acc[BN/16];
  #pragma unroll
  for (int ct = 0; ct < BN/16; ct++) acc[ct] = (floatx4){0.f,0.f,0.f,0.f};

  for (int kc = 0; kc < KC; kc += 64){
    int kb = kbase + kc;
    #pragma unroll
    for (int u = tid; u < 512; u += 256){
      int r = u >> 3, s = u & 7;
      *(uint4*)&Asl[r][s*8] = *(const uint4*)(Abf + ((size_t)(m0+r) << 11) + kb + s*8);
    }
    #pragma unroll
    for (int u = tid; u < BN*8; u += 256){
      int n = u >> 3, s = u & 7;
      *(uint4*)&Bsl[n][s*8] = *(const uint4*)(BtG + ((size_t)n << 11) + kb + s*8);
    }
    __syncthreads();
    #pragma unroll
    for (int k0 = 0; k0 < 64; k0 += 32){
      bf16x8 af = *(const bf16x8*)&Asl[16*w + ml][k0 + quad*8];
      #pragma unroll
      for (int ct = 0; ct < BN/16; ct++){
        bf16x8 bfr = *(const bf16x8*)&Bsl[16*ct + ml][k0 + quad*8];
        acc[ct] = __builtin_amdgcn_mfma_f32_16x16x32_bf16(af, bfr, acc[ct], 0, 0, 0);
      }
    }
    __syncthreads();
  }
  float* C = Cp + (size_t)blockIdx.y * (N * BN);
  #pragma unroll
  for (int ct = 0; ct < BN/16; ct++)
    #pragma unroll
    for (int r = 0; r < 4; r++){
      int row = m0 + 16*w + quad*4 + r;
      C[(size_t)row*BN + 16*ct + ml] = acc[ct][r];
    }
}

// ---------- z1 layers via MFMA, fused gather (p0/p1) + partial-sum (p2/p3) ----------
__global__ __launch_bounds__(256) void k_z1m(
    const unsigned short* __restrict__ hb,
    const int* __restrict__ nidx, const float* __restrict__ ncos,
    const float* __restrict__ df,
    const float* __restrict__ Y1p, const float* __restrict__ dA,
    const float* __restrict__ WF1, const float* __restrict__ WC1,
    const float* __restrict__ WT1, const float* __restrict__ bF1,
    const float* __restrict__ bC1, const float* __restrict__ bT1,
    float* __restrict__ z1f, float* __restrict__ z1cf,
    unsigned short* __restrict__ ZsT){
  __shared__ __align__(16) unsigned short Vs[64][72];
  __shared__ __align__(16) unsigned short Ws[64][72];
  __shared__ __align__(16) unsigned short Tb[64][72];
  __shared__ float bias[64], dAl[64];
  int p = blockIdx.y, i0 = blockIdx.x * 64, tid = threadIdx.x;
  int w = tid >> 6, lane = tid & 63;
  const float* Wsrc = (p == 0) ? WF1 : (p == 2) ? WT1 : WC1;
  const float* bsrc = (p == 0) ? bF1 : (p == 2) ? bT1 : bC1;
  for (int u = tid; u < 1024; u += 256){
    int r = u >> 4, c4 = (u & 15)*4;
    float4 f = *(const float4*)(Wsrc + (size_t)r*H + c4);
    Ws[r][c4+0] = f2bf(f.x); Ws[r][c4+1] = f2bf(f.y);
    Ws[r][c4+2] = f2bf(f.z); Ws[r][c4+3] = f2bf(f.w);
  }
  if (tid < 64){ bias[tid] = bsrc[tid]; dAl[tid] = dA[i0 + tid]; }
  if (p < 2){
    for (int rr = 0; rr < 16; rr++){
      int r = w*16 + rr, i = i0 + r;
      int j0 = nidx[i*4], j1 = nidx[i*4+1], j2 = nidx[i*4+2], j3 = nidx[i*4+3];
      float di = df[i];
      float w0 = ncos[i*4]  *di*df[j0];
      float w1 = ncos[i*4+1]*di*df[j1];
      float w2 = ncos[i*4+2]*di*df[j2];
      float w3 = ncos[i*4+3]*di*df[j3];
      float v = w0*bf2f(hb[(size_t)j0*H+lane]) + w1*bf2f(hb[(size_t)j1*H+lane])
              + w2*bf2f(hb[(size_t)j2*H+lane]) + w3*bf2f(hb[(size_t)j3*H+lane]);
      Vs[r][lane] = f2bf(v);
    }
  } else {
    for (int u = tid; u < 1024; u += 256){
      int r = u >> 4, k4 = u & 15;
      const float* base = Y1p + (size_t)(i0 + r)*H + k4*4;
      float4 s = *(const float4*)base;
      #pragma unroll
      for (int pp = 1; pp < S1; pp++){
        float4 v2 = *(const float4*)(base + (size_t)pp*N*H);
        s.x += v2.x; s.y += v2.y; s.z += v2.z; s.w += v2.w;
      }
      float d = dA[i0 + r];
      Vs[r][k4*4+0] = f2bf(s.x*d); Vs[r][k4*4+1] = f2bf(s.y*d);
      Vs[r][k4*4+2] = f2bf(s.z*d); Vs[r][k4*4+3] = f2bf(s.w*d);
    }
  }
  __syncthreads();
  int quad = lane >> 4, ml = lane & 15;
  floatx4 acc[4];
  #pragma unroll
  for (int ct = 0; ct < 4; ct++) acc[ct] = (floatx4){0.f,0.f,0.f,0.f};
  #pragma unroll
  for (int k0 = 0; k0 < 64; k0 += 32){
    bf16x8 af = *(const bf16x8*)&Vs[16*w + ml][k0 + quad*8];
    #pragma unroll
    for (int ct = 0; ct < 4; ct++){
      bf16x8 bfr = *(const bf16x8*)&Ws[16*ct + ml][k0 + quad*8];
      acc[ct] = __builtin_amdgcn_mfma_f32_16x16x32_bf16(af, bfr, acc[ct], 0, 0, 0);
    }
  }
  if (p < 2){
    float* dst = (p == 0) ? z1f : z1cf;
    #pragma unroll
    for (int ct = 0; ct < 4; ct++){
      int col = 16*ct + ml;
      #pragma unroll
      for (int r = 0; r < 4; r++){
        int row = 16*w + quad*4 + r;
        dst[(size_t)(i0+row)*H + col] = leaky(acc[ct][r] + bias[col]);
      }
    }
  } else {
    #pragma unroll
    for (int ct = 0; ct < 4; ct++){
      int col = 16*ct + ml;
      #pragma unroll
      for (int r = 0; r < 4; r++){
        int row = 16*w + quad*4 + r;
        Tb[col][row] = f2bf(dAl[row] * leaky(acc[ct][r] + bias[col]));
      }
    }
    __syncthreads();
    int zb = (p == 2) ? 0 : 64;
    #pragma unroll
    for (int u = tid; u < 512; u += 256){
      int c = u >> 3, s = u & 7;
      *(uint4*)&ZsT[(size_t)(zb + c)*N + i0 + s*8] = *(uint4*)&Tb[c][s*8];
    }
  }
}

// ---------- z2 layers via MFMA, fused gather (p0/p1) + partial-sum (p2/p3) ----------
__global__ __launch_bounds__(256) void k_z2m(
    const float* __restrict__ z1f, const float* __restrict__ z1cf,
    const int* __restrict__ nidx, const float* __restrict__ ncos,
    const float* __restrict__ df,
    const float* __restrict__ Y2p, const float* __restrict__ dA,
    const float* __restrict__ WF2, const float* __restrict__ WC2,
    const float* __restrict__ WT2, const float* __restrict__ bF2,
    const float* __restrict__ bC2, const float* __restrict__ bT2,
    float* __restrict__ Z6){
  __shared__ __align__(16) unsigned short Vs[64][72];
  __shared__ __align__(16) unsigned short Ws[64][72];
  __shared__ float bias[64];
  int p = blockIdx.y, i0 = blockIdx.x * 64, tid = threadIdx.x;
  int w = tid >> 6, lane = tid & 63;
  const float* Wsrc = (p == 0) ? WF2 : (p == 2) ? WT2 : WC2;
  const float* bsrc = (p == 0) ? bF2 : (p == 2) ? bT2 : bC2;
  for (int u = tid; u < 1024; u += 256){
    int r = u >> 4, c4 = (u & 15)*4;
    float4 f = *(const float4*)(Wsrc + (size_t)r*H + c4);
    Ws[r][c4+0] = f2bf(f.x); Ws[r][c4+1] = f2bf(f.y);
    Ws[r][c4+2] = f2bf(f.z); Ws[r][c4+3] = f2bf(f.w);
  }
  if (tid < 64) bias[tid] = bsrc[tid];
  if (p < 2){
    const float* src = (p == 0) ? z1f : z1cf;
    for (int rr = 0; rr < 16; rr++){
      int r = w*16 + rr, i = i0 + r;
      int j0 = nidx[i*4], j1 = nidx[i*4+1], j2 = nidx[i*4+2], j3 = nidx[i*4+3];
      float di = df[i];
      float w0 = ncos[i*4]  *di*df[j0];
      float w1 = ncos[i*4+1]*di*df[j1];
      float w2 = ncos[i*4+2]*di*df[j2];
      float w3 = ncos[i*4+3]*di*df[j3];
      float v = w0*src[(size_t)j0*H+lane] + w1*src[(size_t)j1*H+lane]
              + w2*src[(size_t)j2*H+lane] + w3*src[(size_t)j3*H+lane];
      Vs[r][lane] = f2bf(v);
    }
  } else {
    int off = (p == 2) ? 0 : 64;
    for (int u = tid; u < 1024; u += 256){
      int r = u >> 4, k4 = u & 15;
      const float* base = Y2p + (size_t)(i0 + r)*128 + off + k4*4;
      float4 s = *(const float4*)base;
      #pragma unroll
      for (int pp = 1; pp < S2; pp++){
        float4 v2 = *(const float4*)(base + (size_t)pp*N*128);
        s.x += v2.x; s.y += v2.y; s.z += v2.z; s.w += v2.w;
      }
      float d = dA[i0 + r];
      Vs[r][k4*4+0] = f2bf(s.x*d); Vs[r][k4*4+1] = f2bf(s.y*d);
      Vs[r][k4*4+2] = f2bf(s.z*d); Vs[r][k4*4+3] = f2bf(s.w*d);
    }
  }
  __syncthreads();
  int quad = lane >> 4, ml = lane & 15;
  floatx4 acc[4];
  #pragma unroll
  for (int ct = 0; ct < 4; ct++) acc[ct] = (floatx4){0.f,0.f,0.f,0.f};
  #pragma unroll
  for (int k0 = 0; k0 < 64; k0 += 32){
    bf16x8 af = *(const bf16x8*)&Vs[16*w + ml][k0 + quad*8];
    #pragma unroll
    for (int ct = 0; ct < 4; ct++){
      bf16x8 bfr = *(const bf16x8*)&Ws[16*ct + ml][k0 + quad*8];
      acc[ct] = __builtin_amdgcn_mfma_f32_16x16x32_bf16(af, bfr, acc[ct], 0, 0, 0);
    }
  }
  int zoff = (p == 0) ? Z_ZF : (p == 1) ? Z_ZCF : (p == 2) ? Z_ZT : Z_ZCT;
  float val[4][4];
  #pragma unroll
  for (int ct = 0; ct < 4; ct++){
    int col = 16*ct + ml;
    #pragma unroll
    for (int r = 0; r < 4; r++){
      val[ct][r] = leaky(acc[ct][r] + bias[col]);
      int row = 16*w + quad*4 + r;
      Z6[(size_t)(i0+row)*384 + zoff + col] = val[ct][r];
    }
  }
  if (p == 1 || p == 3){
    int loff = (p == 1) ? Z_LCF : Z_LCT;
    #pragma unroll
    for (int r = 0; r < 4; r++){
      float s = val[0][r]*val[0][r] + val[1][r]*val[1][r]
              + val[2][r]*val[2][r] + val[3][r]*val[3][r];
      s += __shfl_xor(s, 1, 64); s += __shfl_xor(s, 2, 64);
      s += __shfl_xor(s, 4, 64); s += __shfl_xor(s, 8, 64);
      float m = sqrtf(s*(1.f/64.f)) + 1e-10f;
      int row = 16*w + quad*4 + r;
      #pragma unroll
      for (int ct = 0; ct < 4; ct++)
        Z6[(size_t)(i0+row)*384 + loff + 16*ct + ml] = val[ct][r]/m;
    }
  }
}

// ---------- fused attention+out (blocks 0..511) and reduce (blocks 512..671) ----------
__global__ __launch_bounds__(256) void k_attred(const float* __restrict__ Z6,
    const float* __restrict__ Wag, const float* __restrict__ ba,
    const float* __restrict__ q, const float* __restrict__ W2g,
    const float* __restrict__ b2, float* __restrict__ out,
    float* __restrict__ redP, float* __restrict__ colP){
  __shared__ float Wal[64][65];
  __shared__ float W2l[448];
  __shared__ float zbuf[4][3][66];
  __shared__ float zagg[4][66];
  __shared__ float sa[64][68];
  __shared__ float sb[64][68];
  int tid = threadIdx.x, w = tid >> 6, t = tid & 63;
  if (blockIdx.x < 512){
    for (int u = tid; u < 1024; u += 256){
      int r = u >> 4, c4 = (u & 15)*4;
      float4 f = ((const float4*)Wag)[u];
      Wal[r][c4+0]=f.x; Wal[r][c4+1]=f.y; Wal[r][c4+2]=f.z; Wal[r][c4+3]=f.w;
    }
    if (tid < 112) *(float4*)&W2l[tid*4] = ((const float4*)W2g)[tid];
    __syncthreads();
    int i = blockIdx.x*4 + w;
    const float* zr = Z6 + (size_t)i*384;
    float zf = zr[Z_ZF + t], zt = zr[Z_ZT + t];
    float zc = 0.5f*(zr[Z_ZCF + t] + zr[Z_ZCT + t]);
    zbuf[w][0][t] = zf; zbuf[w][1][t] = zt; zbuf[w][2][t] = zc;
    __syncthreads();
    float bav = ba[t], qv = q[t];
    float e[3];
    #pragma unroll
    for (int k = 0; k < 3; k++){
      float S = bav;
      #pragma unroll 8
      for (int c = 0; c < 64; c++) S += zbuf[w][k][c] * Wal[t][c];
      e[k] = waveRedSum(tanhf(S)*qv);
    }
    float mx = fmaxf(e[0], fmaxf(e[1], e[2]));
    float x0 = expf(e[0]-mx), x1 = expf(e[1]-mx), x2 = expf(e[2]-mx);
    float inv = 1.f/(x0+x1+x2);
    zagg[w][t] = x0*inv*zf + x1*inv*zt + x2*inv*zc;
    __syncthreads();
    if (t < OUTD){
      float acc = b2[t];
      #pragma unroll 8
      for (int c = 0; c < 64; c++) acc += zagg[w][c]*W2l[t*64 + c];
      out[(size_t)i*OUTD + t] = acc;
    }
  } else {
    int bb = blockIdx.x - 512;
    int p = bb >> 5, s = bb & 31;
    const int aoffT[5] = {Z_ZT,  Z_ZF,  Z_LCF, Z_LCF, Z_LCT};
    const int boffT[5] = {Z_ZCT, Z_ZCF, Z_LCF, Z_LCT, Z_LCT};
    int aoff = aoffT[p], boff = boffT[p];
    int r0 = s * 64;
    {
      int row = tid >> 4, c4 = (tid & 15) * 4;
      #pragma unroll
      for (int rr = 0; rr < 64; rr += 16){
        const float* zr = Z6 + (size_t)(r0 + row + rr) * 384;
        *(float4*)&sa[row + rr][c4] = *(const float4*)&zr[aoff + c4];
        *(float4*)&sb[row + rr][c4] = *(const float4*)&zr[boff + c4];
      }
    }
    __syncthreads();
    int rg = tid >> 4, cg = tid & 15;
    float acc[4][4] = {};
    #pragma unroll 8
    for (int k = 0; k < 64; k++){
      float a[4], b[4];
      *(float4*)a = *(const float4*)&sa[k][rg*4];
      *(float4*)b = *(const float4*)&sb[k][cg*4];
      #pragma unroll
      for (int ii = 0; ii < 4; ii++)
        #pragma unroll
        for (int jj = 0; jj < 4; jj++)
          acc[ii][jj] += a[ii]*b[jj];
    }
    float* rp = redP + (size_t)bb * 4096;
    #pragma unroll
    for (int ii = 0; ii < 4; ii++)
      *(float4*)&rp[(rg*4+ii)*64 + cg*4] =
        make_float4(acc[ii][0], acc[ii][1], acc[ii][2], acc[ii][3]);
    if (p < 2 && tid < 128){
      int tt = tid & 63;
      float csum = 0.f;
      if (tid < 64){
        #pragma unroll 16
        for (int r = 0; r < 64; r++) csum += sa[r][tt];
      } else {
        #pragma unroll 16
        for (int r = 0; r < 64; r++) csum += sb[r][tt];
      }
      colP[((size_t)p*RS + s)*128 + tid] = csum;
    }
  }
}

// ---------- sum partial slabs into red ----------
__global__ void k_combine(const float* __restrict__ redP,
                          const float* __restrict__ colP,
                          float* __restrict__ red){
  int idx = blockIdx.x*256 + threadIdx.x;
  if (idx < 20480){
    int p = idx >> 12, i = idx & 4095;
    float sum = 0.f;
    #pragma unroll 8
    for (int s = 0; s < RS; s++) sum += redP[((size_t)p*RS + s)*4096 + i];
    red[idx] = sum;
  } else if (idx < 20736){
    int j = idx - 20480;
    int p = j >> 7, rem = j & 127;
    float sum = 0.f;
    #pragma unroll 8
    for (int s = 0; s < RS; s++) sum += colP[((size_t)p*RS + s)*128 + rem];
    red[idx] = sum;
  }
}

// ---------- final scalars Lc, Ld ----------
__global__ void k_final(const float* __restrict__ red, float* __restrict__ out2){
  int tid = threadIdx.x;
  const float* Stc = red;
  const float* Sfc = red + 4096;
  const float* Cff = red + 8192;
  const float* Cft = red + 12288;
  const float* Ctt = red + 16384;
  const float* cst = red + 20480;
  const float* csct= red + 20544;
  const float* csf = red + 20608;
  const float* cscf= red + 20672;
  float sCff=0, sCft=0, sCtt=0, sM1=0, sM2=0;
  for (int u = tid*16; u < tid*16+16; u++){
    int d = u >> 6, e = u & 63;
    float m1 = Stc[u] - cst[d]*csct[e]*(1.f/2048.f);
    float m2 = Sfc[u] - csf[d]*cscf[e]*(1.f/2048.f);
    sM1 += m1*m1; sM2 += m2*m2;
    float cf = Cff[u], cx = Cft[u], ct = Ctt[u];
    sCff += cf*cf; sCft += cx*cx; sCtt += ct*ct;
  }
  __shared__ float rd[5][4];
  sCff = waveRedSum(sCff); sCft = waveRedSum(sCft); sCtt = waveRedSum(sCtt);
  sM1 = waveRedSum(sM1);   sM2 = waveRedSum(sM2);
  int w = tid >> 6, lane = tid & 63;
  if (lane == 0){ rd[0][w]=sCff; rd[1][w]=sCft; rd[2][w]=sCtt; rd[3][w]=sM1; rd[4][w]=sM2; }
  __syncthreads();
  if (tid == 0){
    float A0 = rd[0][0]+rd[0][1]+rd[0][2]+rd[0][3];
    float A1 = rd[1][0]+rd[1][1]+rd[1][2]+rd[1][3];
    float A2 = rd[2][0]+rd[2][1]+rd[2][2]+rd[2][3];
    float M1 = rd[3][0]+rd[3][1]+rd[3][2]+rd[3][3];
    float M2 = rd[4][0]+rd[4][1]+rd[4][2]+rd[4][3];
    out2[0] = (A0 - 2.f*A1 + A2) * (1.f/(2048.f*2048.f));
    out2[1] = (M1 + M2) * (1.f/(2047.f*2047.f));
  }
}

extern "C" void kernel_launch(void* const* d_in, const int* in_sizes, int n_in,
                              void* d_out, int out_size, void* d_ws, size_t ws_size,
                              hipStream_t stream) {
  const float* x   = (const float*)d_in[0];
  const float* A   = (const float*)d_in[1];
  const float* W1  = (const float*)d_in[3];
  const float* b1  = (const float*)d_in[4];
  const float* WF1 = (const float*)d_in[5];
  const float* bF1 = (const float*)d_in[6];
  const float* WF2 = (const float*)d_in[7];
  const float* bF2 = (const float*)d_in[8];
  const float* WT1 = (const float*)d_in[9];
  const float* bT1 = (const float*)d_in[10];
  const float* WT2 = (const float*)d_in[11];
  const float* bT2 = (const float*)d_in[12];
  const float* WC1 = (const float*)d_in[13];
  const float* bC1 = (const float*)d_in[14];
  const float* WC2 = (const float*)d_in[15];
  const float* bC2 = (const float*)d_in[16];
  const float* Wa  = (const float*)d_in[17];
  const float* ba  = (const float*)d_in[18];
  const float* q   = (const float*)d_in[19];
  const float* W2  = (const float*)d_in[20];
  const float* b2  = (const float*)d_in[21];
  float* out = (float*)d_out;

  float* W = (float*)d_ws;
  float* dA   = W;                      // N
  float* sq   = dA  + N;                // N
  float* hsum = sq  + N;                // N
  float* df   = hsum+ N;                // N
  int*   nidx = (int*)(df + N);         // N*4
  float* ncos = (float*)(nidx + N*4);   // N*4
  float* red  = ncos + N*4;             // 20736
  float* DOT  = red + 20736;            // N*N
  float* Z6   = DOT + (size_t)N*N;      // N*384
  float* Y1p  = Z6  + (size_t)N*384;    // S1*N*H
  float* Y2p  = Y1p + (size_t)S1*N*H;   // S2*N*128
  float* z1f  = Y2p + (size_t)S2*N*128; // N*H
  float* z1cf = z1f + N*H;              // N*H
  float* redP = z1cf+ N*H;              // 5*RS*4096 = 655360
  float* colP = redP+ 655360;           // 2*RS*128 = 8192
  unsigned short* Abf  = (unsigned short*)(colP + 8192);  // N*N bf16
  unsigned short* hsT  = Abf + (size_t)N*N;               // 64*N
  unsigned short* ZsT  = hsT + (size_t)H*N;               // 128*N
  unsigned short* hbHi = ZsT + (size_t)128*N;             // N*64
  unsigned short* hbLo = hbHi + (size_t)N*H;              // N*64

  k_preph<<<128, 256, 0, stream>>>(A, x, W1, b1, dA, Abf, hbHi, hbLo, hsT, sq, hsum);
  k_gram2<<<dim3(16,16), 256, 0, stream>>>(hbHi, hbLo, DOT);
  k_topk<<<512, 256, 0, stream>>>(DOT, sq, hsum, nidx, ncos, df);
  k_mgemm<64><<<dim3(32,S1), 256, 0, stream>>>(Abf, hsT, Y1p, N/S1);
  k_z1m<<<dim3(32,4), 256, 0, stream>>>(hbHi, nidx, ncos, df, Y1p, dA,
                                        WF1, WC1, WT1, bF1, bC1, bT1,
                                        z1f, z1cf, ZsT);
  k_mgemm<128><<<dim3(32,S2), 256, 0, stream>>>(Abf, ZsT, Y2p, N/S2);
  k_z2m<<<dim3(32,4), 256, 0, stream>>>(z1f, z1cf, nidx, ncos, df, Y2p, dA,
                                        WF2, WC2, WT2, bF2, bC2, bT2, Z6);
  k_attred<<<672, 256, 0, stream>>>(Z6, Wa, ba, q, W2, b2, out, redP, colP);
  k_combine<<<81, 256, 0, stream>>>(redP, colP, red);
  k_final<<<1, 256, 0, stream>>>(red, out + (size_t)N*OUTD);
}